// Round 17
// baseline (505.365 us; speedup 1.0000x reference)
//
#include <hip/hip_runtime.h>
#include <hip/hip_bf16.h>

#define B_   32
#define C_   256
#define HH   64
#define P_   4096   // 64*64
#define L_   40
#define D_   768
#define NC_  8
#define EMB_ 392
#define CP_  (C_*P_)   // 1048576
#define LOS  264      // epilogue LDS row stride (shorts)
#define PADW 132      // k_final fp32 transpose row stride (floats), 16B-aligned

typedef __attribute__((ext_vector_type(8))) short bf16x8;
typedef __attribute__((ext_vector_type(4))) float f32x4;
typedef unsigned short u16;

// fast transcendentals (hot epilogues only; k_lang keeps libm)
static __device__ __forceinline__ float silu_fast(float y) {
    return __fdividef(y, 1.f + __expf(-y));
}
static __device__ __forceinline__ float tanh_fast(float x) {
    return 1.f - __fdividef(2.f, __expf(2.f * x) + 1.f);
}
static __device__ __forceinline__ u16 f2b(float f) {
    __hip_bfloat16 h = __float2bfloat16(f);
    return *reinterpret_cast<u16*>(&h);
}
static __device__ __forceinline__ float b2f(u16 u) {
    unsigned v = ((unsigned)u) << 16;
    return __int_as_float((int)v);
}

typedef __attribute__((address_space(1))) const unsigned int g_u32;
typedef __attribute__((address_space(3))) unsigned int l_u32;
static __device__ __forceinline__ void gl_lds(const u16* g, short* l) {
    __builtin_amdgcn_global_load_lds((g_u32*)g, (l_u32*)l, 16, 0, 0);
}
#define VMCNT6() asm volatile("s_waitcnt vmcnt(6)" ::: "memory")
#define VMCNT0() asm volatile("s_waitcnt vmcnt(0)" ::: "memory")
#define RBAR()  do { __builtin_amdgcn_s_barrier(); __builtin_amdgcn_sched_barrier(0); } while (0)

// ---------------- weight pack to bf16 + zero block ----------------
__global__ __launch_bounds__(256) void k_prep(
    const float* __restrict__ wv, const float* __restrict__ wf1,
    const float* __restrict__ wf3, const float* __restrict__ wf2,
    u16* __restrict__ WV, u16* __restrict__ WF1,
    u16* __restrict__ WF3, u16* __restrict__ WF2, u16* __restrict__ zbig)
{
    int i = blockIdx.x * 256 + threadIdx.x;   // i = oc*256 + ic
    int oc = i >> 8, ic = i & 255;
    WV[i]  = f2b(wv[i]);
    WF1[i] = f2b(wf1[i]);
    WF3[i] = f2b(wf3[i]);
#pragma unroll
    for (int tap = 0; tap < 9; ++tap)
        WF2[oc * 2304 + tap * 256 + ic] = f2b(wf2[oc * 2304 + ic * 9 + tap]);
    if (blockIdx.x == 0) {
        for (int z = threadIdx.x; z < 1024; z += 256) zbig[z] = 0;
    }
}

// ---------------- img -> channels-last bf16 ----------------
__global__ __launch_bounds__(256) void k_imgT(
    const float* __restrict__ img, u16* __restrict__ imgT)
{
    int b = blockIdx.z, pix0 = blockIdx.x * 32, ic0 = blockIdx.y * 32;
    int t = threadIdx.x;
    __shared__ float T[32][33];
    int ic = t >> 3, ps = (t & 7) * 4;
    f32x4 v = *(const f32x4*)&img[((size_t)b * C_ + ic0 + ic) * P_ + pix0 + ps];
    T[ic][ps] = v[0]; T[ic][ps + 1] = v[1]; T[ic][ps + 2] = v[2]; T[ic][ps + 3] = v[3];
    __syncthreads();
    int px = t >> 3, sg = (t & 7) * 4;
    u16 o0 = f2b(T[sg + 0][px]), o1 = f2b(T[sg + 1][px]);
    u16 o2 = f2b(T[sg + 2][px]), o3 = f2b(T[sg + 3][px]);
    uint2 val;
    val.x = (unsigned)o0 | ((unsigned)o1 << 16);
    val.y = (unsigned)o2 | ((unsigned)o3 << 16);
    *(uint2*)(imgT + ((size_t)b * P_ + pix0 + px) * C_ + ic0 + sg) = val;
}

// ---------------- language path (fp32, precise libm) ----------------
__global__ __launch_bounds__(256) void k_lang(
    const float* __restrict__ flang, const int* __restrict__ wmask,
    const float* __restrict__ W1, const float* __restrict__ b1,
    const float* __restrict__ W2, const float* __restrict__ b2,
    int* __restrict__ centers)
{
    int b = blockIdx.x, tid = threadIdx.x;
    __shared__ float inner[L_];
    __shared__ float cnt_s;
    __shared__ float favg[D_];
    __shared__ float hbuf[EMB_];
    __shared__ float mfs[16];

    if (tid == 0) {
        int total = 0;
        for (int l = 0; l < L_; ++l) total += wmask[b * L_ + l];
        int c = 0, cntv = 0;
        for (int l = 0; l < L_; ++l) {
            int m = wmask[b * L_ + l];
            c += m;
            float f = (m == 1 && c > 1 && c < total) ? 1.f : 0.f;
            inner[l] = f;
            cntv += (f != 0.f);
        }
        cnt_s = (float)cntv;
    }
    __syncthreads();
    float cinv = 1.f / cnt_s;
    for (int d = tid; d < D_; d += 256) {
        float s = 0.f;
        for (int l = 0; l < L_; ++l)
            s += flang[((size_t)b * L_ + l) * D_ + d] * inner[l];
        favg[d] = s * cinv;
    }
    __syncthreads();
    for (int e = tid; e < EMB_; e += 256) {
        float s = b1[e];
        const float* w = W1 + (size_t)e * D_;
        for (int d = 0; d < D_; ++d) s += w[d] * favg[d];
        hbuf[e] = s;
    }
    __syncthreads();
    if (tid < 16) {
        float s = b2[tid];
        const float* w = W2 + tid * EMB_;
        for (int d = 0; d < EMB_; ++d) s += w[d] * hbuf[d];
        mfs[tid] = 1.f / (1.f + expf(-s));
    }
    __syncthreads();
    if (tid < NC_) {
        centers[b * (NC_ * 2) + tid * 2 + 0] = (int)(mfs[tid * 2 + 0] * (float)HH);
        centers[b * (NC_ * 2) + tid * 2 + 1] = (int)(mfs[tid * 2 + 1] * (float)HH);
    }
}

// ---------------- gaussian -> gamma/beta maps (fast transcendentals) ----------------
__global__ __launch_bounds__(256) void k_gb(
    const int* __restrict__ centers,
    const float* __restrict__ wg, const float* __restrict__ sg, const float* __restrict__ bg,
    const float* __restrict__ wb, const float* __restrict__ sb, const float* __restrict__ bb,
    float* __restrict__ gmap, float* __restrict__ bmap)
{
    int idx = blockIdx.x * 256 + threadIdx.x;
    int b = idx >> 12;
    int p = idx & 4095;
    int gy = p >> 6, gx = p & 63;

    float w[NC_];
#pragma unroll
    for (int nc = 0; nc < NC_; ++nc) {
        int yc = centers[b * (NC_ * 2) + nc * 2 + 0];
        int xc = centers[b * (NC_ * 2) + nc * 2 + 1];
        int dy = gy - yc, dx = gx - xc;
        w[nc] = __expf(-(float)(dy * dy + dx * dx) / 81.92f);
    }
    float gsum = 0.f, bmx = -1e30f;
#pragma unroll
    for (int c = 0; c < NC_; ++c) {
        float ag = 0.f, ab = 0.f;
#pragma unroll
        for (int ic = 0; ic < NC_; ++ic) {
            ag += wg[c * NC_ + ic] * w[ic];
            ab += wb[c * NC_ + ic] * w[ic];
        }
        gsum += tanh_fast(silu_fast(sg[c] * ag + bg[c]));
        bmx = fmaxf(bmx, tanh_fast(silu_fast(sb[c] * ab + bb[c])));
    }
    gmap[idx] = gsum * (1.f / (float)NC_);
    bmap[idx] = bmx;
}

// ---------------- MFMA helpers ----------------
static __device__ __forceinline__ void frag_load(const short* sA, const short* sW,
                                                 int l15, int qa, int w,
                                                 bf16x8 a[8], bf16x8 bb[4])
{
#pragma unroll
    for (int m = 0; m < 8; ++m)
        a[m] = *(const bf16x8*)&sA[(m * 16 + l15) * 32 + qa * 8];
#pragma unroll
    for (int n = 0; n < 4; ++n)
        bb[n] = *(const bf16x8*)&sW[(w * 64 + n * 16 + l15) * 32 + qa * 8];
}
static __device__ __forceinline__ void frag_compute(const bf16x8 a[8], const bf16x8 bb[4],
                                                    f32x4 acc[8][4])
{
#pragma unroll
    for (int m = 0; m < 8; ++m)
#pragma unroll
        for (int n = 0; n < 4; ++n)
            acc[m][n] = __builtin_amdgcn_mfma_f32_16x16x32_bf16(a[m], bb[n], acc[m][n], 0, 0, 0);
}

// ---------------- visu conv + FiLM + l2norm -> v_film (bf16 CL) ----------------
__global__ __launch_bounds__(256, 2) void k_visu(
    const u16* __restrict__ X, const u16* __restrict__ W,
    const float* __restrict__ s_visu, const float* __restrict__ b_visu,
    const float* __restrict__ gmap, const float* __restrict__ bmap,
    u16* __restrict__ Y)
{
    int b = blockIdx.y, p0 = blockIdx.x * 128, t = threadIdx.x;
    int lane = t & 63, w = t >> 6;
    int l15 = t & 15, q = (t >> 4) & 3;
    int qa = q ^ ((l15 >> 1) & 3);
    int lc = (lane & 3) ^ ((lane >> 3) & 3);
    int lp = lane >> 2;
    __shared__ __align__(16) short SM[3 * 12288];   // 73728 B; epilogue LO = 67584 B
    __shared__ float red[4][128];
    __shared__ float invs[128];
    const u16* Xb = X + (size_t)b * CP_;

    f32x4 acc[8][4];
#pragma unroll
    for (int m = 0; m < 8; ++m)
#pragma unroll
        for (int n = 0; n < 4; ++n) acc[m][n] = (f32x4)0.f;

    auto stage = [&](int s, int buf) {
        int k0 = s * 32;
        short* bA = SM + buf * 12288;
        short* bW = bA + 4096;
#pragma unroll
        for (int i = 0; i < 2; ++i) {
            int pr = (w * 2 + i) * 16 + lp;
            gl_lds(Xb + (size_t)(p0 + pr) * C_ + k0 + lc * 8, bA + (w * 2 + i) * 512);
        }
#pragma unroll
        for (int j = 0; j < 4; ++j) {
            int oc = (w * 4 + j) * 16 + lp;
            gl_lds(W + (size_t)oc * 256 + k0 + lc * 8, bW + (w * 4 + j) * 512);
        }
    };

    stage(0, 0);
    stage(1, 1);
    VMCNT6();
    RBAR();
    int cur = 0;
    for (int s = 0; s < 8; ++s) {
        const short* bA = SM + cur * 12288;
        bf16x8 a[8], bb[4];
        frag_load(bA, bA + 4096, l15, qa, w, a, bb);
        if (s < 6) stage(s + 2, (cur == 0) ? 2 : cur - 1);
        frag_compute(a, bb, acc);
        if (s < 6) { VMCNT6(); } else { VMCNT0(); }
        RBAR();
        cur = (cur == 2) ? 0 : cur + 1;
    }

    float sc[4], sh[4];
#pragma unroll
    for (int n = 0; n < 4; ++n) {
        int oc = w * 64 + n * 16 + l15;
        sc[n] = s_visu[oc]; sh[n] = b_visu[oc];
    }
    short* LO = SM;
#pragma unroll
    for (int m = 0; m < 8; ++m) {
        f32x4 gv = *(const f32x4*)&gmap[(size_t)b * P_ + p0 + m * 16 + q * 4];
        f32x4 bm = *(const f32x4*)&bmap[(size_t)b * P_ + p0 + m * 16 + q * 4];
        float ps[4] = {0.f, 0.f, 0.f, 0.f};
#pragma unroll
        for (int n = 0; n < 4; ++n)
#pragma unroll
            for (int r = 0; r < 4; ++r) {
                float y = sc[n] * acc[m][n][r] + sh[n];
                float v = gv[r] * tanh_fast(silu_fast(y)) + bm[r];
                ps[r] += v * v;
                LO[(m * 16 + q * 4 + r) * LOS + w * 64 + n * 16 + l15] = (short)f2b(v);
            }
#pragma unroll
        for (int r = 0; r < 4; ++r) {
            float p = ps[r];
            p += __shfl_xor(p, 1);
            p += __shfl_xor(p, 2);
            p += __shfl_xor(p, 4);
            p += __shfl_xor(p, 8);
            if (l15 == 0) red[w][m * 16 + q * 4 + r] = p;
        }
    }
    __syncthreads();
    if (t < 128) {
        float s = red[0][t] + red[1][t] + red[2][t] + red[3][t];
        invs[t] = 1.f / fmaxf(sqrtf(s), 1e-12f);
    }
    __syncthreads();

    u16* Yb = Y + (size_t)b * CP_ + (size_t)p0 * C_;
#pragma unroll
    for (int h = 0; h < 2; ++h) {
        int row = h * 64 + (t >> 2);
        float inv = invs[row];
        const short* sp = &LO[row * LOS];
        u16* dp = Yb + (size_t)row * C_;
#pragma unroll
        for (int u = 0; u < 8; ++u) {
            int c = (t & 3) * 8 + u * 32;
            uint4 vv = *(const uint4*)(sp + c);
            const u16* e = (const u16*)&vv;
            uint4 o;
            u16* oe = (u16*)&o;
#pragma unroll
            for (int k = 0; k < 8; ++k) oe[k] = f2b(b2f(e[k]) * inv);
            *(uint4*)(dp + c) = o;
        }
    }
}

// ---------------- 1x1 conv (f1) + silu -> bf16 CL ----------------
__global__ __launch_bounds__(256, 2) void k_f1(
    const u16* __restrict__ X, const u16* __restrict__ W,
    const float* __restrict__ scale, const float* __restrict__ shift,
    u16* __restrict__ Y)
{
    int b = blockIdx.y, p0 = blockIdx.x * 128, t = threadIdx.x;
    int lane = t & 63, w = t >> 6;
    int l15 = t & 15, q = (t >> 4) & 3;
    int qa = q ^ ((l15 >> 1) & 3);
    int lc = (lane & 3) ^ ((lane >> 3) & 3);
    int lp = lane >> 2;
    __shared__ __align__(16) short SM[3 * 12288];
    const u16* Xb = X + (size_t)b * CP_;

    f32x4 acc[8][4];
#pragma unroll
    for (int m = 0; m < 8; ++m)
#pragma unroll
        for (int n = 0; n < 4; ++n) acc[m][n] = (f32x4)0.f;

    auto stage = [&](int s, int buf) {
        int k0 = s * 32;
        short* bA = SM + buf * 12288;
        short* bW = bA + 4096;
#pragma unroll
        for (int i = 0; i < 2; ++i) {
            int pr = (w * 2 + i) * 16 + lp;
            gl_lds(Xb + (size_t)(p0 + pr) * C_ + k0 + lc * 8, bA + (w * 2 + i) * 512);
        }
#pragma unroll
        for (int j = 0; j < 4; ++j) {
            int oc = (w * 4 + j) * 16 + lp;
            gl_lds(W + (size_t)oc * 256 + k0 + lc * 8, bW + (w * 4 + j) * 512);
        }
    };

    stage(0, 0);
    stage(1, 1);
    VMCNT6();
    RBAR();
    int cur = 0;
    for (int s = 0; s < 8; ++s) {
        const short* bA = SM + cur * 12288;
        bf16x8 a[8], bb[4];
        frag_load(bA, bA + 4096, l15, qa, w, a, bb);
        if (s < 6) stage(s + 2, (cur == 0) ? 2 : cur - 1);
        frag_compute(a, bb, acc);
        if (s < 6) { VMCNT6(); } else { VMCNT0(); }
        RBAR();
        cur = (cur == 2) ? 0 : cur + 1;
    }

    float sc[4], sh[4];
#pragma unroll
    for (int n = 0; n < 4; ++n) {
        int oc = w * 64 + n * 16 + l15;
        sc[n] = scale[oc]; sh[n] = shift[oc];
    }
    short* LO = SM;
#pragma unroll
    for (int m = 0; m < 8; ++m)
#pragma unroll
        for (int n = 0; n < 4; ++n)
#pragma unroll
            for (int r = 0; r < 4; ++r) {
                float v = silu_fast(sc[n] * acc[m][n][r] + sh[n]);
                LO[(m * 16 + q * 4 + r) * LOS + w * 64 + n * 16 + l15] = (short)f2b(v);
            }
    __syncthreads();

    u16* Yb = Y + (size_t)b * CP_ + (size_t)p0 * C_;
#pragma unroll
    for (int h = 0; h < 2; ++h) {
        int row = h * 64 + (t >> 2);
        const short* sp = &LO[row * LOS];
        u16* dp = Yb + (size_t)row * C_;
#pragma unroll
        for (int u = 0; u < 8; ++u) {
            int c = (t & 3) * 8 + u * 32;
            *(uint4*)(dp + c) = *(const uint4*)(sp + c);
        }
    }
}

// ---------------- 3x3 conv (f2) + silu -> bf16 CL (3-buffer, incremental pointers) ----------------
__global__ __launch_bounds__(256, 2) void k_f2(
    const u16* __restrict__ X, const u16* __restrict__ W,
    const float* __restrict__ scale, const float* __restrict__ shift,
    const u16* __restrict__ zbig, u16* __restrict__ Y)
{
    int b = blockIdx.y, p0 = blockIdx.x * 128, t = threadIdx.x;
    int lane = t & 63, w = t >> 6;
    int l15 = t & 15, q = (t >> 4) & 3;
    int qa = q ^ ((l15 >> 1) & 3);
    int lc = (lane & 3) ^ ((lane >> 3) & 3);
    int lp = lane >> 2;
    __shared__ __align__(16) short SM[3 * 12288];   // 73728 B
    const u16* Xb = X + (size_t)b * CP_;

    f32x4 acc[8][4];
#pragma unroll
    for (int m = 0; m < 8; ++m)
#pragma unroll
        for (int n = 0; n < 4; ++n) acc[m][n] = (f32x4)0.f;

    // incremental staging state: one K-step per stage_next() call
    const u16* ap0 = zbig;
    const u16* ap1 = zbig;
    const u16* wp0 = W + (size_t)((w * 4 + 0) * 16 + lp) * 2304 + lc * 8;
    const u16* wp1 = W + (size_t)((w * 4 + 1) * 16 + lp) * 2304 + lc * 8;
    const u16* wp2 = W + (size_t)((w * 4 + 2) * 16 + lp) * 2304 + lc * 8;
    const u16* wp3 = W + (size_t)((w * 4 + 3) * 16 + lp) * 2304 + lc * 8;
    int ss = 0;

    auto stage_next = [&](int buf) {
        if ((ss & 7) == 0) {
            int tap = ss >> 3;
            int dy = tap / 3 - 1, dx = tap - (tap / 3) * 3 - 1;
            int pA = p0 + (w * 2 + 0) * 16 + lp;
            int y0 = (pA >> 6) + dy, x0 = (pA & 63) + dx;
            ap0 = ((unsigned)y0 < (unsigned)HH && (unsigned)x0 < (unsigned)HH)
                  ? Xb + (size_t)(y0 * HH + x0) * C_ + lc * 8 : zbig + lc * 8;
            int pB = p0 + (w * 2 + 1) * 16 + lp;
            int y1 = (pB >> 6) + dy, x1 = (pB & 63) + dx;
            ap1 = ((unsigned)y1 < (unsigned)HH && (unsigned)x1 < (unsigned)HH)
                  ? Xb + (size_t)(y1 * HH + x1) * C_ + lc * 8 : zbig + lc * 8;
        }
        short* bA = SM + buf * 12288;
        short* bW = bA + 4096;
        gl_lds(ap0, bA + (w * 2 + 0) * 512);
        gl_lds(ap1, bA + (w * 2 + 1) * 512);
        gl_lds(wp0, bW + (w * 4 + 0) * 512);
        gl_lds(wp1, bW + (w * 4 + 1) * 512);
        gl_lds(wp2, bW + (w * 4 + 2) * 512);
        gl_lds(wp3, bW + (w * 4 + 3) * 512);
        ap0 += 32; ap1 += 32;
        wp0 += 32; wp1 += 32; wp2 += 32; wp3 += 32;
        ++ss;
    };

    stage_next(0);
    stage_next(1);
    VMCNT6();
    RBAR();
    int cur = 0;
    for (int s = 0; s < 72; ++s) {
        const short* bA = SM + cur * 12288;
        bf16x8 a[8], bb[4];
        frag_load(bA, bA + 4096, l15, qa, w, a, bb);
        if (s < 70) {
            int nb = cur == 0 ? 2 : cur - 1;   // (cur+2)%3
            stage_next(nb);
        }
        frag_compute(a, bb, acc);
        if (s < 70) { VMCNT6(); } else { VMCNT0(); }
        RBAR();
        cur = cur == 2 ? 0 : cur + 1;
    }

    float sc[4], sh[4];
#pragma unroll
    for (int n = 0; n < 4; ++n) {
        int oc = w * 64 + n * 16 + l15;
        sc[n] = scale[oc]; sh[n] = shift[oc];
    }
    short* LO = SM;
#pragma unroll
    for (int m = 0; m < 8; ++m)
#pragma unroll
        for (int n = 0; n < 4; ++n)
#pragma unroll
            for (int r = 0; r < 4; ++r) {
                float v = silu_fast(sc[n] * acc[m][n][r] + sh[n]);
                LO[(m * 16 + q * 4 + r) * LOS + w * 64 + n * 16 + l15] = (short)f2b(v);
            }
    __syncthreads();

    u16* Yb = Y + (size_t)b * CP_ + (size_t)p0 * C_;
#pragma unroll
    for (int h = 0; h < 2; ++h) {
        int row = h * 64 + (t >> 2);
        const short* sp = &LO[row * LOS];
        u16* dp = Yb + (size_t)row * C_;
#pragma unroll
        for (int u = 0; u < 8; ++u) {
            int c = (t & 3) * 8 + u * 32;
            *(uint4*)(dp + c) = *(const uint4*)(sp + c);
        }
    }
}

// ---------------- f3 conv + bias + v_add + l2norm -> out (fp32 CF, coalesced stores) ----------------
__global__ __launch_bounds__(256, 2) void k_final(
    const u16* __restrict__ X, const u16* __restrict__ W,
    const float* __restrict__ bias_f3, const float* __restrict__ img,
    const float* __restrict__ add_w, float* __restrict__ out)
{
    int b = blockIdx.y, p0 = blockIdx.x * 128, t = threadIdx.x;
    int lane = t & 63, w = t >> 6;
    int l15 = t & 15, q = (t >> 4) & 3;
    int qa = q ^ ((l15 >> 1) & 3);
    int lc = (lane & 3) ^ ((lane >> 3) & 3);
    int lp = lane >> 2;
    __shared__ __align__(16) short SM[3 * 12288];   // 73728 B; TP uses 128*PADW*4 = 67584 B
    __shared__ float red[4][128];
    __shared__ float invs[128];
    const u16* Xb = X + (size_t)b * CP_;

    f32x4 acc[8][4];
#pragma unroll
    for (int m = 0; m < 8; ++m)
#pragma unroll
        for (int n = 0; n < 4; ++n) acc[m][n] = (f32x4)0.f;

    auto stage = [&](int s, int buf) {
        int k0 = s * 32;
        short* bA = SM + buf * 12288;
        short* bW = bA + 4096;
#pragma unroll
        for (int i = 0; i < 2; ++i) {
            int pr = (w * 2 + i) * 16 + lp;
            gl_lds(Xb + (size_t)(p0 + pr) * C_ + k0 + lc * 8, bA + (w * 2 + i) * 512);
        }
#pragma unroll
        for (int j = 0; j < 4; ++j) {
            int oc = (w * 4 + j) * 16 + lp;
            gl_lds(W + (size_t)oc * 256 + k0 + lc * 8, bW + (w * 4 + j) * 512);
        }
    };

    stage(0, 0);
    stage(1, 1);
    VMCNT6();
    RBAR();
    int cur = 0;
    for (int s = 0; s < 8; ++s) {
        const short* bA = SM + cur * 12288;
        bf16x8 a[8], bb[4];
        frag_load(bA, bA + 4096, l15, qa, w, a, bb);
        if (s < 6) stage(s + 2, (cur == 0) ? 2 : cur - 1);
        frag_compute(a, bb, acc);
        if (s < 6) { VMCNT6(); } else { VMCNT0(); }
        RBAR();
        cur = (cur == 2) ? 0 : cur + 1;
    }

    float aw = tanhf(add_w[0]);
    float c1 = 1.f + aw, c2 = 1.f - aw;
    float bf[4];
#pragma unroll
    for (int n = 0; n < 4; ++n) bf[n] = bias_f3[w * 64 + n * 16 + l15];

#pragma unroll
    for (int m = 0; m < 8; ++m) {
        float ps[4] = {0.f, 0.f, 0.f, 0.f};
#pragma unroll
        for (int n = 0; n < 4; ++n) {
            int oc = w * 64 + n * 16 + l15;
            f32x4 iv = *(const f32x4*)&img[((size_t)b * C_ + oc) * P_ + p0 + m * 16 + q * 4];
#pragma unroll
            for (int r = 0; r < 4; ++r) {
                float v = c1 * iv[r] + c2 * (acc[m][n][r] + bf[n]);
                acc[m][n][r] = v;
                ps[r] += v * v;
            }
        }
#pragma unroll
        for (int r = 0; r < 4; ++r) {
            float p = ps[r];
            p += __shfl_xor(p, 1);
            p += __shfl_xor(p, 2);
            p += __shfl_xor(p, 4);
            p += __shfl_xor(p, 8);
            if (l15 == 0) red[w][m * 16 + q * 4 + r] = p;
        }
    }
    __syncthreads();
    if (t < 128) {
        float s = red[0][t] + red[1][t] + red[2][t] + red[3][t];
        invs[t] = 1.f / fmaxf(sqrtf(s), 1e-12f);
    }
    __syncthreads();

    // coalesced store via LDS transpose: 2 chunks of 128 oc
    float* TP = (float*)SM;   // [128][PADW] f32
#pragma unroll
    for (int cc = 0; cc < 2; ++cc) {
        if ((w >> 1) == cc) {
            int wl = w & 1;   // 0..1 within chunk, owns oc rows wl*64..wl*64+63
#pragma unroll
            for (int m = 0; m < 8; ++m) {
                f32x4 iv = *(const f32x4*)&invs[m * 16 + q * 4];
#pragma unroll
                for (int n = 0; n < 4; ++n) {
                    f32x4 o;
#pragma unroll
                    for (int r = 0; r < 4; ++r) o[r] = acc[m][n][r] * iv[r];
                    *(f32x4*)&TP[(size_t)(wl * 64 + n * 16 + l15) * PADW + m * 16 + q * 4] = o;
                }
            }
        }
        __syncthreads();
        {
            int row = t >> 1, pb = (t & 1) * 64;
            float* dp = &out[((size_t)b * C_ + cc * 128 + row) * P_ + p0 + pb];
            const float* sp = &TP[(size_t)row * PADW + pb];
#pragma unroll
            for (int u = 0; u < 16; ++u)
                *(f32x4*)(dp + u * 4) = *(const f32x4*)(sp + u * 4);
        }
        __syncthreads();
    }
}

extern "C" void kernel_launch(void* const* d_in, const int* in_sizes, int n_in,
                              void* d_out, int out_size, void* d_ws, size_t ws_size,
                              hipStream_t stream)
{
    const float* img     = (const float*)d_in[0];
    const float* flang   = (const float*)d_in[1];
    const int*   wmask   = (const int*)d_in[2];
    const float* w_visu  = (const float*)d_in[3];
    const float* s_visu  = (const float*)d_in[4];
    const float* b_visu  = (const float*)d_in[5];
    const float* w_g     = (const float*)d_in[6];
    const float* s_g     = (const float*)d_in[7];
    const float* b_g     = (const float*)d_in[8];
    const float* w_b     = (const float*)d_in[9];
    const float* s_b     = (const float*)d_in[10];
    const float* b_b     = (const float*)d_in[11];
    const float* W1      = (const float*)d_in[12];
    const float* b1      = (const float*)d_in[13];
    const float* W2      = (const float*)d_in[14];
    const float* b2      = (const float*)d_in[15];
    const float* w_f1    = (const float*)d_in[16];
    const float* s_f1    = (const float*)d_in[17];
    const float* b_f1    = (const float*)d_in[18];
    const float* w_f2    = (const float*)d_in[19];
    const float* s_f2    = (const float*)d_in[20];
    const float* b_f2    = (const float*)d_in[21];
    const float* w_f3    = (const float*)d_in[22];
    const float* bias_f3 = (const float*)d_in[23];
    const float* add_w   = (const float*)d_in[24];

    float* out = (float*)d_out;

    // workspace layout (u16 elements)
    u16* bigA = (u16*)d_ws;                 // 33554432: v_film, then v2
    u16* bigB = bigA + (size_t)B_ * CP_;    // 33554432: imgT, then v
    u16* WV   = bigB + (size_t)B_ * CP_;    // 65536
    u16* WF1  = WV + 65536;                 // 65536
    u16* WF3  = WF1 + 65536;                // 65536
    u16* WF2  = WF3 + 65536;                // 589824
    float* gmap = (float*)(WF2 + 589824);   // 131072 f32
    float* bmap = gmap + (size_t)B_ * P_;   // 131072 f32
    int* centers = (int*)(bmap + (size_t)B_ * P_);  // 512 ints
    u16* zbig = (u16*)(centers + 512);      // 1024 u16 zero block

    k_prep<<<256, 256, 0, stream>>>(w_visu, w_f1, w_f3, w_f2, WV, WF1, WF3, WF2, zbig);
    k_lang<<<B_, 256, 0, stream>>>(flang, wmask, W1, b1, W2, b2, centers);
    k_gb<<<(B_ * P_) / 256, 256, 0, stream>>>(centers, w_g, s_g, b_g, w_b, s_b, b_b, gmap, bmap);
    k_imgT<<<dim3(P_ / 32, C_ / 32, B_), 256, 0, stream>>>(img, bigB);
    k_visu<<<dim3(P_ / 128, B_), 256, 0, stream>>>(bigB, WV, s_visu, b_visu, gmap, bmap, bigA);
    k_f1<<<dim3(P_ / 128, B_), 256, 0, stream>>>(bigA, WF1, s_f1, b_f1, bigB);
    k_f2<<<dim3(P_ / 128, B_), 256, 0, stream>>>(bigB, WF2, s_f2, b_f2, zbig, bigA);
    k_final<<<dim3(P_ / 128, B_), 256, 0, stream>>>(bigA, WF3, bias_f3, img, add_w, out);
}

// Round 18
// 443.459 us; speedup vs baseline: 1.1396x; 1.1396x over previous
//
#include <hip/hip_runtime.h>
#include <hip/hip_bf16.h>

#define B_   32
#define C_   256
#define HH   64
#define P_   4096   // 64*64
#define L_   40
#define D_   768
#define NC_  8
#define EMB_ 392
#define CP_  (C_*P_)   // 1048576
#define LOS  264      // epilogue LDS row stride (shorts)

typedef __attribute__((ext_vector_type(8))) short bf16x8;
typedef __attribute__((ext_vector_type(4))) float f32x4;
typedef unsigned short u16;

// fast transcendentals (hot epilogues only; k_lang keeps libm)
static __device__ __forceinline__ float silu_fast(float y) {
    return __fdividef(y, 1.f + __expf(-y));
}
static __device__ __forceinline__ float tanh_fast(float x) {
    return 1.f - __fdividef(2.f, __expf(2.f * x) + 1.f);
}
static __device__ __forceinline__ u16 f2b(float f) {
    __hip_bfloat16 h = __float2bfloat16(f);
    return *reinterpret_cast<u16*>(&h);
}
static __device__ __forceinline__ float b2f(u16 u) {
    unsigned v = ((unsigned)u) << 16;
    return __int_as_float((int)v);
}

typedef __attribute__((address_space(1))) const unsigned int g_u32;
typedef __attribute__((address_space(3))) unsigned int l_u32;
static __device__ __forceinline__ void gl_lds(const u16* g, short* l) {
    __builtin_amdgcn_global_load_lds((g_u32*)g, (l_u32*)l, 16, 0, 0);
}
#define VMCNT6() asm volatile("s_waitcnt vmcnt(6)" ::: "memory")
#define VMCNT0() asm volatile("s_waitcnt vmcnt(0)" ::: "memory")
#define RBAR()  do { __builtin_amdgcn_s_barrier(); __builtin_amdgcn_sched_barrier(0); } while (0)

// ---------------- weight pack to bf16 + zero block ----------------
__global__ __launch_bounds__(256) void k_prep(
    const float* __restrict__ wv, const float* __restrict__ wf1,
    const float* __restrict__ wf3, const float* __restrict__ wf2,
    u16* __restrict__ WV, u16* __restrict__ WF1,
    u16* __restrict__ WF3, u16* __restrict__ WF2, u16* __restrict__ zbig)
{
    int i = blockIdx.x * 256 + threadIdx.x;   // i = oc*256 + ic
    int oc = i >> 8, ic = i & 255;
    WV[i]  = f2b(wv[i]);
    WF1[i] = f2b(wf1[i]);
    WF3[i] = f2b(wf3[i]);
#pragma unroll
    for (int tap = 0; tap < 9; ++tap)
        WF2[oc * 2304 + tap * 256 + ic] = f2b(wf2[oc * 2304 + ic * 9 + tap]);
    if (blockIdx.x == 0) {
        for (int z = threadIdx.x; z < 1024; z += 256) zbig[z] = 0;
    }
}

// ---------------- img -> channels-last bf16 ----------------
__global__ __launch_bounds__(256) void k_imgT(
    const float* __restrict__ img, u16* __restrict__ imgT)
{
    int b = blockIdx.z, pix0 = blockIdx.x * 32, ic0 = blockIdx.y * 32;
    int t = threadIdx.x;
    __shared__ float T[32][33];
    int ic = t >> 3, ps = (t & 7) * 4;
    f32x4 v = *(const f32x4*)&img[((size_t)b * C_ + ic0 + ic) * P_ + pix0 + ps];
    T[ic][ps] = v[0]; T[ic][ps + 1] = v[1]; T[ic][ps + 2] = v[2]; T[ic][ps + 3] = v[3];
    __syncthreads();
    int px = t >> 3, sg = (t & 7) * 4;
    u16 o0 = f2b(T[sg + 0][px]), o1 = f2b(T[sg + 1][px]);
    u16 o2 = f2b(T[sg + 2][px]), o3 = f2b(T[sg + 3][px]);
    uint2 val;
    val.x = (unsigned)o0 | ((unsigned)o1 << 16);
    val.y = (unsigned)o2 | ((unsigned)o3 << 16);
    *(uint2*)(imgT + ((size_t)b * P_ + pix0 + px) * C_ + ic0 + sg) = val;
}

// ---------------- language path (fp32, precise libm) ----------------
__global__ __launch_bounds__(256) void k_lang(
    const float* __restrict__ flang, const int* __restrict__ wmask,
    const float* __restrict__ W1, const float* __restrict__ b1,
    const float* __restrict__ W2, const float* __restrict__ b2,
    int* __restrict__ centers)
{
    int b = blockIdx.x, tid = threadIdx.x;
    __shared__ float inner[L_];
    __shared__ float cnt_s;
    __shared__ float favg[D_];
    __shared__ float hbuf[EMB_];
    __shared__ float mfs[16];

    if (tid == 0) {
        int total = 0;
        for (int l = 0; l < L_; ++l) total += wmask[b * L_ + l];
        int c = 0, cntv = 0;
        for (int l = 0; l < L_; ++l) {
            int m = wmask[b * L_ + l];
            c += m;
            float f = (m == 1 && c > 1 && c < total) ? 1.f : 0.f;
            inner[l] = f;
            cntv += (f != 0.f);
        }
        cnt_s = (float)cntv;
    }
    __syncthreads();
    float cinv = 1.f / cnt_s;
    for (int d = tid; d < D_; d += 256) {
        float s = 0.f;
        for (int l = 0; l < L_; ++l)
            s += flang[((size_t)b * L_ + l) * D_ + d] * inner[l];
        favg[d] = s * cinv;
    }
    __syncthreads();
    for (int e = tid; e < EMB_; e += 256) {
        float s = b1[e];
        const float* w = W1 + (size_t)e * D_;
        for (int d = 0; d < D_; ++d) s += w[d] * favg[d];
        hbuf[e] = s;
    }
    __syncthreads();
    if (tid < 16) {
        float s = b2[tid];
        const float* w = W2 + tid * EMB_;
        for (int d = 0; d < EMB_; ++d) s += w[d] * hbuf[d];
        mfs[tid] = 1.f / (1.f + expf(-s));
    }
    __syncthreads();
    if (tid < NC_) {
        centers[b * (NC_ * 2) + tid * 2 + 0] = (int)(mfs[tid * 2 + 0] * (float)HH);
        centers[b * (NC_ * 2) + tid * 2 + 1] = (int)(mfs[tid * 2 + 1] * (float)HH);
    }
}

// ---------------- gaussian -> gamma/beta maps (fast transcendentals) ----------------
__global__ __launch_bounds__(256) void k_gb(
    const int* __restrict__ centers,
    const float* __restrict__ wg, const float* __restrict__ sg, const float* __restrict__ bg,
    const float* __restrict__ wb, const float* __restrict__ sb, const float* __restrict__ bb,
    float* __restrict__ gmap, float* __restrict__ bmap)
{
    int idx = blockIdx.x * 256 + threadIdx.x;
    int b = idx >> 12;
    int p = idx & 4095;
    int gy = p >> 6, gx = p & 63;

    float w[NC_];
#pragma unroll
    for (int nc = 0; nc < NC_; ++nc) {
        int yc = centers[b * (NC_ * 2) + nc * 2 + 0];
        int xc = centers[b * (NC_ * 2) + nc * 2 + 1];
        int dy = gy - yc, dx = gx - xc;
        w[nc] = __expf(-(float)(dy * dy + dx * dx) / 81.92f);
    }
    float gsum = 0.f, bmx = -1e30f;
#pragma unroll
    for (int c = 0; c < NC_; ++c) {
        float ag = 0.f, ab = 0.f;
#pragma unroll
        for (int ic = 0; ic < NC_; ++ic) {
            ag += wg[c * NC_ + ic] * w[ic];
            ab += wb[c * NC_ + ic] * w[ic];
        }
        gsum += tanh_fast(silu_fast(sg[c] * ag + bg[c]));
        bmx = fmaxf(bmx, tanh_fast(silu_fast(sb[c] * ab + bb[c])));
    }
    gmap[idx] = gsum * (1.f / (float)NC_);
    bmap[idx] = bmx;
}

// ---------------- MFMA helpers ----------------
static __device__ __forceinline__ void frag_load(const short* sA, const short* sW,
                                                 int l15, int qa, int w,
                                                 bf16x8 a[8], bf16x8 bb[4])
{
#pragma unroll
    for (int m = 0; m < 8; ++m)
        a[m] = *(const bf16x8*)&sA[(m * 16 + l15) * 32 + qa * 8];
#pragma unroll
    for (int n = 0; n < 4; ++n)
        bb[n] = *(const bf16x8*)&sW[(w * 64 + n * 16 + l15) * 32 + qa * 8];
}
static __device__ __forceinline__ void frag_compute(const bf16x8 a[8], const bf16x8 bb[4],
                                                    f32x4 acc[8][4])
{
#pragma unroll
    for (int m = 0; m < 8; ++m)
#pragma unroll
        for (int n = 0; n < 4; ++n)
            acc[m][n] = __builtin_amdgcn_mfma_f32_16x16x32_bf16(a[m], bb[n], acc[m][n], 0, 0, 0);
}

// ---------------- visu conv + FiLM + l2norm -> v_film (bf16 CL) ----------------
__global__ __launch_bounds__(256, 2) void k_visu(
    const u16* __restrict__ X, const u16* __restrict__ W,
    const float* __restrict__ s_visu, const float* __restrict__ b_visu,
    const float* __restrict__ gmap, const float* __restrict__ bmap,
    u16* __restrict__ Y)
{
    int b = blockIdx.y, p0 = blockIdx.x * 128, t = threadIdx.x;
    int lane = t & 63, w = t >> 6;
    int l15 = t & 15, q = (t >> 4) & 3;
    int qa = q ^ ((l15 >> 1) & 3);
    int lc = (lane & 3) ^ ((lane >> 3) & 3);
    int lp = lane >> 2;
    __shared__ __align__(16) short SM[3 * 12288];   // 73728 B; epilogue LO = 67584 B
    __shared__ float red[4][128];
    __shared__ float invs[128];
    const u16* Xb = X + (size_t)b * CP_;

    f32x4 acc[8][4];
#pragma unroll
    for (int m = 0; m < 8; ++m)
#pragma unroll
        for (int n = 0; n < 4; ++n) acc[m][n] = (f32x4)0.f;

    auto stage = [&](int s, int buf) {
        int k0 = s * 32;
        short* bA = SM + buf * 12288;
        short* bW = bA + 4096;
#pragma unroll
        for (int i = 0; i < 2; ++i) {
            int pr = (w * 2 + i) * 16 + lp;
            gl_lds(Xb + (size_t)(p0 + pr) * C_ + k0 + lc * 8, bA + (w * 2 + i) * 512);
        }
#pragma unroll
        for (int j = 0; j < 4; ++j) {
            int oc = (w * 4 + j) * 16 + lp;
            gl_lds(W + (size_t)oc * 256 + k0 + lc * 8, bW + (w * 4 + j) * 512);
        }
    };

    stage(0, 0);
    stage(1, 1);
    VMCNT6();
    RBAR();
    int cur = 0;
    for (int s = 0; s < 8; ++s) {
        const short* bA = SM + cur * 12288;
        bf16x8 a[8], bb[4];
        frag_load(bA, bA + 4096, l15, qa, w, a, bb);
        if (s < 6) stage(s + 2, (cur == 0) ? 2 : cur - 1);
        frag_compute(a, bb, acc);
        if (s < 6) { VMCNT6(); } else { VMCNT0(); }
        RBAR();
        cur = (cur == 2) ? 0 : cur + 1;
    }

    float sc[4], sh[4];
#pragma unroll
    for (int n = 0; n < 4; ++n) {
        int oc = w * 64 + n * 16 + l15;
        sc[n] = s_visu[oc]; sh[n] = b_visu[oc];
    }
    short* LO = SM;
#pragma unroll
    for (int m = 0; m < 8; ++m) {
        f32x4 gv = *(const f32x4*)&gmap[(size_t)b * P_ + p0 + m * 16 + q * 4];
        f32x4 bm = *(const f32x4*)&bmap[(size_t)b * P_ + p0 + m * 16 + q * 4];
        float ps[4] = {0.f, 0.f, 0.f, 0.f};
#pragma unroll
        for (int n = 0; n < 4; ++n)
#pragma unroll
            for (int r = 0; r < 4; ++r) {
                float y = sc[n] * acc[m][n][r] + sh[n];
                float v = gv[r] * tanh_fast(silu_fast(y)) + bm[r];
                ps[r] += v * v;
                LO[(m * 16 + q * 4 + r) * LOS + w * 64 + n * 16 + l15] = (short)f2b(v);
            }
#pragma unroll
        for (int r = 0; r < 4; ++r) {
            float p = ps[r];
            p += __shfl_xor(p, 1);
            p += __shfl_xor(p, 2);
            p += __shfl_xor(p, 4);
            p += __shfl_xor(p, 8);
            if (l15 == 0) red[w][m * 16 + q * 4 + r] = p;
        }
    }
    __syncthreads();
    if (t < 128) {
        float s = red[0][t] + red[1][t] + red[2][t] + red[3][t];
        invs[t] = 1.f / fmaxf(sqrtf(s), 1e-12f);
    }
    __syncthreads();

    u16* Yb = Y + (size_t)b * CP_ + (size_t)p0 * C_;
#pragma unroll
    for (int h = 0; h < 2; ++h) {
        int row = h * 64 + (t >> 2);
        float inv = invs[row];
        const short* sp = &LO[row * LOS];
        u16* dp = Yb + (size_t)row * C_;
#pragma unroll
        for (int u = 0; u < 8; ++u) {
            int c = (t & 3) * 8 + u * 32;
            uint4 vv = *(const uint4*)(sp + c);
            const u16* e = (const u16*)&vv;
            uint4 o;
            u16* oe = (u16*)&o;
#pragma unroll
            for (int k = 0; k < 8; ++k) oe[k] = f2b(b2f(e[k]) * inv);
            *(uint4*)(dp + c) = o;
        }
    }
}

// ---------------- 1x1 conv (f1) + silu -> bf16 CL ----------------
__global__ __launch_bounds__(256, 2) void k_f1(
    const u16* __restrict__ X, const u16* __restrict__ W,
    const float* __restrict__ scale, const float* __restrict__ shift,
    u16* __restrict__ Y)
{
    int b = blockIdx.y, p0 = blockIdx.x * 128, t = threadIdx.x;
    int lane = t & 63, w = t >> 6;
    int l15 = t & 15, q = (t >> 4) & 3;
    int qa = q ^ ((l15 >> 1) & 3);
    int lc = (lane & 3) ^ ((lane >> 3) & 3);
    int lp = lane >> 2;
    __shared__ __align__(16) short SM[3 * 12288];
    const u16* Xb = X + (size_t)b * CP_;

    f32x4 acc[8][4];
#pragma unroll
    for (int m = 0; m < 8; ++m)
#pragma unroll
        for (int n = 0; n < 4; ++n) acc[m][n] = (f32x4)0.f;

    auto stage = [&](int s, int buf) {
        int k0 = s * 32;
        short* bA = SM + buf * 12288;
        short* bW = bA + 4096;
#pragma unroll
        for (int i = 0; i < 2; ++i) {
            int pr = (w * 2 + i) * 16 + lp;
            gl_lds(Xb + (size_t)(p0 + pr) * C_ + k0 + lc * 8, bA + (w * 2 + i) * 512);
        }
#pragma unroll
        for (int j = 0; j < 4; ++j) {
            int oc = (w * 4 + j) * 16 + lp;
            gl_lds(W + (size_t)oc * 256 + k0 + lc * 8, bW + (w * 4 + j) * 512);
        }
    };

    stage(0, 0);
    stage(1, 1);
    VMCNT6();
    RBAR();
    int cur = 0;
    for (int s = 0; s < 8; ++s) {
        const short* bA = SM + cur * 12288;
        bf16x8 a[8], bb[4];
        frag_load(bA, bA + 4096, l15, qa, w, a, bb);
        if (s < 6) stage(s + 2, (cur == 0) ? 2 : cur - 1);
        frag_compute(a, bb, acc);
        if (s < 6) { VMCNT6(); } else { VMCNT0(); }
        RBAR();
        cur = (cur == 2) ? 0 : cur + 1;
    }

    float sc[4], sh[4];
#pragma unroll
    for (int n = 0; n < 4; ++n) {
        int oc = w * 64 + n * 16 + l15;
        sc[n] = scale[oc]; sh[n] = shift[oc];
    }
    short* LO = SM;
#pragma unroll
    for (int m = 0; m < 8; ++m)
#pragma unroll
        for (int n = 0; n < 4; ++n)
#pragma unroll
            for (int r = 0; r < 4; ++r) {
                float v = silu_fast(sc[n] * acc[m][n][r] + sh[n]);
                LO[(m * 16 + q * 4 + r) * LOS + w * 64 + n * 16 + l15] = (short)f2b(v);
            }
    __syncthreads();

    u16* Yb = Y + (size_t)b * CP_ + (size_t)p0 * C_;
#pragma unroll
    for (int h = 0; h < 2; ++h) {
        int row = h * 64 + (t >> 2);
        const short* sp = &LO[row * LOS];
        u16* dp = Yb + (size_t)row * C_;
#pragma unroll
        for (int u = 0; u < 8; ++u) {
            int c = (t & 3) * 8 + u * 32;
            *(uint4*)(dp + c) = *(const uint4*)(sp + c);
        }
    }
}

// ---------------- 3x3 conv (f2) + silu -> bf16 CL (3-buffer, incremental pointers) ----------------
__global__ __launch_bounds__(256, 2) void k_f2(
    const u16* __restrict__ X, const u16* __restrict__ W,
    const float* __restrict__ scale, const float* __restrict__ shift,
    const u16* __restrict__ zbig, u16* __restrict__ Y)
{
    int b = blockIdx.y, p0 = blockIdx.x * 128, t = threadIdx.x;
    int lane = t & 63, w = t >> 6;
    int l15 = t & 15, q = (t >> 4) & 3;
    int qa = q ^ ((l15 >> 1) & 3);
    int lc = (lane & 3) ^ ((lane >> 3) & 3);
    int lp = lane >> 2;
    __shared__ __align__(16) short SM[3 * 12288];   // 73728 B
    const u16* Xb = X + (size_t)b * CP_;

    f32x4 acc[8][4];
#pragma unroll
    for (int m = 0; m < 8; ++m)
#pragma unroll
        for (int n = 0; n < 4; ++n) acc[m][n] = (f32x4)0.f;

    // incremental staging state: one K-step per stage_next() call
    const u16* ap0 = zbig;
    const u16* ap1 = zbig;
    const u16* wp0 = W + (size_t)((w * 4 + 0) * 16 + lp) * 2304 + lc * 8;
    const u16* wp1 = W + (size_t)((w * 4 + 1) * 16 + lp) * 2304 + lc * 8;
    const u16* wp2 = W + (size_t)((w * 4 + 2) * 16 + lp) * 2304 + lc * 8;
    const u16* wp3 = W + (size_t)((w * 4 + 3) * 16 + lp) * 2304 + lc * 8;
    int ss = 0;

    auto stage_next = [&](int buf) {
        if ((ss & 7) == 0) {
            int tap = ss >> 3;
            int dy = tap / 3 - 1, dx = tap - (tap / 3) * 3 - 1;
            int pA = p0 + (w * 2 + 0) * 16 + lp;
            int y0 = (pA >> 6) + dy, x0 = (pA & 63) + dx;
            ap0 = ((unsigned)y0 < (unsigned)HH && (unsigned)x0 < (unsigned)HH)
                  ? Xb + (size_t)(y0 * HH + x0) * C_ + lc * 8 : zbig + lc * 8;
            int pB = p0 + (w * 2 + 1) * 16 + lp;
            int y1 = (pB >> 6) + dy, x1 = (pB & 63) + dx;
            ap1 = ((unsigned)y1 < (unsigned)HH && (unsigned)x1 < (unsigned)HH)
                  ? Xb + (size_t)(y1 * HH + x1) * C_ + lc * 8 : zbig + lc * 8;
        }
        short* bA = SM + buf * 12288;
        short* bW = bA + 4096;
        gl_lds(ap0, bA + (w * 2 + 0) * 512);
        gl_lds(ap1, bA + (w * 2 + 1) * 512);
        gl_lds(wp0, bW + (w * 4 + 0) * 512);
        gl_lds(wp1, bW + (w * 4 + 1) * 512);
        gl_lds(wp2, bW + (w * 4 + 2) * 512);
        gl_lds(wp3, bW + (w * 4 + 3) * 512);
        ap0 += 32; ap1 += 32;
        wp0 += 32; wp1 += 32; wp2 += 32; wp3 += 32;
        ++ss;
    };

    stage_next(0);
    stage_next(1);
    VMCNT6();
    RBAR();
    int cur = 0;
    for (int s = 0; s < 72; ++s) {
        const short* bA = SM + cur * 12288;
        bf16x8 a[8], bb[4];
        frag_load(bA, bA + 4096, l15, qa, w, a, bb);
        if (s < 70) {
            int nb = cur == 0 ? 2 : cur - 1;   // (cur+2)%3
            stage_next(nb);
        }
        frag_compute(a, bb, acc);
        if (s < 70) { VMCNT6(); } else { VMCNT0(); }
        RBAR();
        cur = cur == 2 ? 0 : cur + 1;
    }

    float sc[4], sh[4];
#pragma unroll
    for (int n = 0; n < 4; ++n) {
        int oc = w * 64 + n * 16 + l15;
        sc[n] = scale[oc]; sh[n] = shift[oc];
    }
    short* LO = SM;
#pragma unroll
    for (int m = 0; m < 8; ++m)
#pragma unroll
        for (int n = 0; n < 4; ++n)
#pragma unroll
            for (int r = 0; r < 4; ++r) {
                float v = silu_fast(sc[n] * acc[m][n][r] + sh[n]);
                LO[(m * 16 + q * 4 + r) * LOS + w * 64 + n * 16 + l15] = (short)f2b(v);
            }
    __syncthreads();

    u16* Yb = Y + (size_t)b * CP_ + (size_t)p0 * C_;
#pragma unroll
    for (int h = 0; h < 2; ++h) {
        int row = h * 64 + (t >> 2);
        const short* sp = &LO[row * LOS];
        u16* dp = Yb + (size_t)row * C_;
#pragma unroll
        for (int u = 0; u < 8; ++u) {
            int c = (t & 3) * 8 + u * 32;
            *(uint4*)(dp + c) = *(const uint4*)(sp + c);
        }
    }
}

// ---------------- f3 conv + bias + v_add + l2norm -> out (fp32 CF, coalesced stores v2) ----------------
__global__ __launch_bounds__(256, 2) void k_final(
    const u16* __restrict__ X, const u16* __restrict__ W,
    const float* __restrict__ bias_f3, const float* __restrict__ img,
    const float* __restrict__ add_w, float* __restrict__ out)
{
    int b = blockIdx.y, p0 = blockIdx.x * 128, t = threadIdx.x;
    int lane = t & 63, w = t >> 6;
    int l15 = t & 15, q = (t >> 4) & 3;
    int qa = q ^ ((l15 >> 1) & 3);
    int lc = (lane & 3) ^ ((lane >> 3) & 3);
    int lp = lane >> 2;
    __shared__ __align__(16) short SM[3 * 12288];   // 73728 B; TP uses 256*68*4 = 69632 B
    __shared__ float red[4][128];
    __shared__ float invs[128];
    const u16* Xb = X + (size_t)b * CP_;

    f32x4 acc[8][4];
#pragma unroll
    for (int m = 0; m < 8; ++m)
#pragma unroll
        for (int n = 0; n < 4; ++n) acc[m][n] = (f32x4)0.f;

    auto stage = [&](int s, int buf) {
        int k0 = s * 32;
        short* bA = SM + buf * 12288;
        short* bW = bA + 4096;
#pragma unroll
        for (int i = 0; i < 2; ++i) {
            int pr = (w * 2 + i) * 16 + lp;
            gl_lds(Xb + (size_t)(p0 + pr) * C_ + k0 + lc * 8, bA + (w * 2 + i) * 512);
        }
#pragma unroll
        for (int j = 0; j < 4; ++j) {
            int oc = (w * 4 + j) * 16 + lp;
            gl_lds(W + (size_t)oc * 256 + k0 + lc * 8, bW + (w * 4 + j) * 512);
        }
    };

    stage(0, 0);
    stage(1, 1);
    VMCNT6();
    RBAR();
    int cur = 0;
    for (int s = 0; s < 8; ++s) {
        const short* bA = SM + cur * 12288;
        bf16x8 a[8], bb[4];
        frag_load(bA, bA + 4096, l15, qa, w, a, bb);
        if (s < 6) stage(s + 2, (cur == 0) ? 2 : cur - 1);
        frag_compute(a, bb, acc);
        if (s < 6) { VMCNT6(); } else { VMCNT0(); }
        RBAR();
        cur = (cur == 2) ? 0 : cur + 1;
    }

    float aw = tanhf(add_w[0]);
    float c1 = 1.f + aw, c2 = 1.f - aw;
    float bf[4];
#pragma unroll
    for (int n = 0; n < 4; ++n) bf[n] = bias_f3[w * 64 + n * 16 + l15];

#pragma unroll
    for (int m = 0; m < 8; ++m) {
        float ps[4] = {0.f, 0.f, 0.f, 0.f};
#pragma unroll
        for (int n = 0; n < 4; ++n) {
            int oc = w * 64 + n * 16 + l15;
            f32x4 iv = *(const f32x4*)&img[((size_t)b * C_ + oc) * P_ + p0 + m * 16 + q * 4];
#pragma unroll
            for (int r = 0; r < 4; ++r) {
                float v = c1 * iv[r] + c2 * (acc[m][n][r] + bf[n]);
                acc[m][n][r] = v;
                ps[r] += v * v;
            }
        }
#pragma unroll
        for (int r = 0; r < 4; ++r) {
            float p = ps[r];
            p += __shfl_xor(p, 1);
            p += __shfl_xor(p, 2);
            p += __shfl_xor(p, 4);
            p += __shfl_xor(p, 8);
            if (l15 == 0) red[w][m * 16 + q * 4 + r] = p;
        }
    }
    __syncthreads();
    if (t < 128) {
        float s = red[0][t] + red[1][t] + red[2][t] + red[3][t];
        invs[t] = 1.f / fmaxf(sqrtf(s), 1e-12f);
    }
    __syncthreads();

    // coalesced store via LDS transpose: 2 chunks of 64 pixels; all waves active
    float* TP = (float*)SM;   // [256 oc][68] f32
#pragma unroll
    for (int cc = 0; cc < 2; ++cc) {
#pragma unroll
        for (int mm = 0; mm < 4; ++mm) {
            int m = cc * 4 + mm;
            f32x4 iv = *(const f32x4*)&invs[m * 16 + q * 4];
#pragma unroll
            for (int n = 0; n < 4; ++n) {
                int oc = w * 64 + n * 16 + l15;
                f32x4 o;
#pragma unroll
                for (int r = 0; r < 4; ++r) o[r] = acc[m][n][r] * iv[r];
                *(f32x4*)&TP[(size_t)oc * 68 + mm * 16 + q * 4] = o;
            }
        }
        __syncthreads();
        {
            int c16 = (t & 15) * 4;
#pragma unroll
            for (int u = 0; u < 16; ++u) {
                int row = u * 16 + (t >> 4);
                *(f32x4*)&out[((size_t)b * C_ + row) * P_ + p0 + cc * 64 + c16] =
                    *(const f32x4*)&TP[(size_t)row * 68 + c16];
            }
        }
        __syncthreads();
    }
}

extern "C" void kernel_launch(void* const* d_in, const int* in_sizes, int n_in,
                              void* d_out, int out_size, void* d_ws, size_t ws_size,
                              hipStream_t stream)
{
    const float* img     = (const float*)d_in[0];
    const float* flang   = (const float*)d_in[1];
    const int*   wmask   = (const int*)d_in[2];
    const float* w_visu  = (const float*)d_in[3];
    const float* s_visu  = (const float*)d_in[4];
    const float* b_visu  = (const float*)d_in[5];
    const float* w_g     = (const float*)d_in[6];
    const float* s_g     = (const float*)d_in[7];
    const float* b_g     = (const float*)d_in[8];
    const float* w_b     = (const float*)d_in[9];
    const float* s_b     = (const float*)d_in[10];
    const float* b_b     = (const float*)d_in[11];
    const float* W1      = (const float*)d_in[12];
    const float* b1      = (const float*)d_in[13];
    const float* W2      = (const float*)d_in[14];
    const float* b2      = (const float*)d_in[15];
    const float* w_f1    = (const float*)d_in[16];
    const float* s_f1    = (const float*)d_in[17];
    const float* b_f1    = (const float*)d_in[18];
    const float* w_f2    = (const float*)d_in[19];
    const float* s_f2    = (const float*)d_in[20];
    const float* b_f2    = (const float*)d_in[21];
    const float* w_f3    = (const float*)d_in[22];
    const float* bias_f3 = (const float*)d_in[23];
    const float* add_w   = (const float*)d_in[24];

    float* out = (float*)d_out;

    // workspace layout (u16 elements)
    u16* bigA = (u16*)d_ws;                 // 33554432: v_film, then v2
    u16* bigB = bigA + (size_t)B_ * CP_;    // 33554432: imgT, then v
    u16* WV   = bigB + (size_t)B_ * CP_;    // 65536
    u16* WF1  = WV + 65536;                 // 65536
    u16* WF3  = WF1 + 65536;                // 65536
    u16* WF2  = WF3 + 65536;                // 589824
    float* gmap = (float*)(WF2 + 589824);   // 131072 f32
    float* bmap = gmap + (size_t)B_ * P_;   // 131072 f32
    int* centers = (int*)(bmap + (size_t)B_ * P_);  // 512 ints
    u16* zbig = (u16*)(centers + 512);      // 1024 u16 zero block

    k_prep<<<256, 256, 0, stream>>>(w_visu, w_f1, w_f3, w_f2, WV, WF1, WF3, WF2, zbig);
    k_lang<<<B_, 256, 0, stream>>>(flang, wmask, W1, b1, W2, b2, centers);
    k_gb<<<(B_ * P_) / 256, 256, 0, stream>>>(centers, w_g, s_g, b_g, w_b, s_b, b_b, gmap, bmap);
    k_imgT<<<dim3(P_ / 32, C_ / 32, B_), 256, 0, stream>>>(img, bigB);
    k_visu<<<dim3(P_ / 128, B_), 256, 0, stream>>>(bigB, WV, s_visu, b_visu, gmap, bmap, bigA);
    k_f1<<<dim3(P_ / 128, B_), 256, 0, stream>>>(bigA, WF1, s_f1, b_f1, bigB);
    k_f2<<<dim3(P_ / 128, B_), 256, 0, stream>>>(bigB, WF2, s_f2, b_f2, zbig, bigA);
    k_final<<<dim3(P_ / 128, B_), 256, 0, stream>>>(bigA, WF3, bias_f3, img, add_w, out);
}

// Round 19
// 434.047 us; speedup vs baseline: 1.1643x; 1.0217x over previous
//
#include <hip/hip_runtime.h>
#include <hip/hip_bf16.h>

#define B_   32
#define C_   256
#define HH   64
#define P_   4096   // 64*64
#define L_   40
#define D_   768
#define NC_  8
#define EMB_ 392
#define CP_  (C_*P_)   // 1048576
#define LOS  264      // epilogue LDS row stride (shorts)

typedef __attribute__((ext_vector_type(8))) short bf16x8;
typedef __attribute__((ext_vector_type(4))) float f32x4;
typedef unsigned short u16;

// fast transcendentals (hot epilogues only; k_lang keeps libm)
static __device__ __forceinline__ float silu_fast(float y) {
    return __fdividef(y, 1.f + __expf(-y));
}
static __device__ __forceinline__ float tanh_fast(float x) {
    return 1.f - __fdividef(2.f, __expf(2.f * x) + 1.f);
}
static __device__ __forceinline__ u16 f2b(float f) {
    __hip_bfloat16 h = __float2bfloat16(f);
    return *reinterpret_cast<u16*>(&h);
}
static __device__ __forceinline__ float b2f(u16 u) {
    unsigned v = ((unsigned)u) << 16;
    return __int_as_float((int)v);
}

typedef __attribute__((address_space(1))) const unsigned int g_u32;
typedef __attribute__((address_space(3))) unsigned int l_u32;
static __device__ __forceinline__ void gl_lds(const u16* g, short* l) {
    __builtin_amdgcn_global_load_lds((g_u32*)g, (l_u32*)l, 16, 0, 0);
}
#define VMCNT6() asm volatile("s_waitcnt vmcnt(6)" ::: "memory")
#define VMCNT4() asm volatile("s_waitcnt vmcnt(4)" ::: "memory")
#define VMCNT0() asm volatile("s_waitcnt vmcnt(0)" ::: "memory")
#define RBAR()  do { __builtin_amdgcn_s_barrier(); __builtin_amdgcn_sched_barrier(0); } while (0)

// ---------------- weight pack to bf16 + zero block ----------------
__global__ __launch_bounds__(256) void k_prep(
    const float* __restrict__ wv, const float* __restrict__ wf1,
    const float* __restrict__ wf3, const float* __restrict__ wf2,
    u16* __restrict__ WV, u16* __restrict__ WF1,
    u16* __restrict__ WF3, u16* __restrict__ WF2, u16* __restrict__ zbig)
{
    int i = blockIdx.x * 256 + threadIdx.x;   // i = oc*256 + ic
    int oc = i >> 8, ic = i & 255;
    WV[i]  = f2b(wv[i]);
    WF1[i] = f2b(wf1[i]);
    WF3[i] = f2b(wf3[i]);
#pragma unroll
    for (int tap = 0; tap < 9; ++tap)
        WF2[oc * 2304 + tap * 256 + ic] = f2b(wf2[oc * 2304 + ic * 9 + tap]);
    if (blockIdx.x == 0) {
        for (int z = threadIdx.x; z < 1024; z += 256) zbig[z] = 0;
    }
}

// ---------------- img -> channels-last bf16 ----------------
__global__ __launch_bounds__(256) void k_imgT(
    const float* __restrict__ img, u16* __restrict__ imgT)
{
    int b = blockIdx.z, pix0 = blockIdx.x * 32, ic0 = blockIdx.y * 32;
    int t = threadIdx.x;
    __shared__ float T[32][33];
    int ic = t >> 3, ps = (t & 7) * 4;
    f32x4 v = *(const f32x4*)&img[((size_t)b * C_ + ic0 + ic) * P_ + pix0 + ps];
    T[ic][ps] = v[0]; T[ic][ps + 1] = v[1]; T[ic][ps + 2] = v[2]; T[ic][ps + 3] = v[3];
    __syncthreads();
    int px = t >> 3, sg = (t & 7) * 4;
    u16 o0 = f2b(T[sg + 0][px]), o1 = f2b(T[sg + 1][px]);
    u16 o2 = f2b(T[sg + 2][px]), o3 = f2b(T[sg + 3][px]);
    uint2 val;
    val.x = (unsigned)o0 | ((unsigned)o1 << 16);
    val.y = (unsigned)o2 | ((unsigned)o3 << 16);
    *(uint2*)(imgT + ((size_t)b * P_ + pix0 + px) * C_ + ic0 + sg) = val;
}

// ---------------- language path (fp32, precise libm) ----------------
__global__ __launch_bounds__(256) void k_lang(
    const float* __restrict__ flang, const int* __restrict__ wmask,
    const float* __restrict__ W1, const float* __restrict__ b1,
    const float* __restrict__ W2, const float* __restrict__ b2,
    int* __restrict__ centers)
{
    int b = blockIdx.x, tid = threadIdx.x;
    __shared__ float inner[L_];
    __shared__ float cnt_s;
    __shared__ float favg[D_];
    __shared__ float hbuf[EMB_];
    __shared__ float mfs[16];

    if (tid == 0) {
        int total = 0;
        for (int l = 0; l < L_; ++l) total += wmask[b * L_ + l];
        int c = 0, cntv = 0;
        for (int l = 0; l < L_; ++l) {
            int m = wmask[b * L_ + l];
            c += m;
            float f = (m == 1 && c > 1 && c < total) ? 1.f : 0.f;
            inner[l] = f;
            cntv += (f != 0.f);
        }
        cnt_s = (float)cntv;
    }
    __syncthreads();
    float cinv = 1.f / cnt_s;
    for (int d = tid; d < D_; d += 256) {
        float s = 0.f;
        for (int l = 0; l < L_; ++l)
            s += flang[((size_t)b * L_ + l) * D_ + d] * inner[l];
        favg[d] = s * cinv;
    }
    __syncthreads();
    for (int e = tid; e < EMB_; e += 256) {
        float s = b1[e];
        const float* w = W1 + (size_t)e * D_;
        for (int d = 0; d < D_; ++d) s += w[d] * favg[d];
        hbuf[e] = s;
    }
    __syncthreads();
    if (tid < 16) {
        float s = b2[tid];
        const float* w = W2 + tid * EMB_;
        for (int d = 0; d < EMB_; ++d) s += w[d] * hbuf[d];
        mfs[tid] = 1.f / (1.f + expf(-s));
    }
    __syncthreads();
    if (tid < NC_) {
        centers[b * (NC_ * 2) + tid * 2 + 0] = (int)(mfs[tid * 2 + 0] * (float)HH);
        centers[b * (NC_ * 2) + tid * 2 + 1] = (int)(mfs[tid * 2 + 1] * (float)HH);
    }
}

// ---------------- gaussian -> gamma/beta maps (fast transcendentals) ----------------
__global__ __launch_bounds__(256) void k_gb(
    const int* __restrict__ centers,
    const float* __restrict__ wg, const float* __restrict__ sg, const float* __restrict__ bg,
    const float* __restrict__ wb, const float* __restrict__ sb, const float* __restrict__ bb,
    float* __restrict__ gmap, float* __restrict__ bmap)
{
    int idx = blockIdx.x * 256 + threadIdx.x;
    int b = idx >> 12;
    int p = idx & 4095;
    int gy = p >> 6, gx = p & 63;

    float w[NC_];
#pragma unroll
    for (int nc = 0; nc < NC_; ++nc) {
        int yc = centers[b * (NC_ * 2) + nc * 2 + 0];
        int xc = centers[b * (NC_ * 2) + nc * 2 + 1];
        int dy = gy - yc, dx = gx - xc;
        w[nc] = __expf(-(float)(dy * dy + dx * dx) / 81.92f);
    }
    float gsum = 0.f, bmx = -1e30f;
#pragma unroll
    for (int c = 0; c < NC_; ++c) {
        float ag = 0.f, ab = 0.f;
#pragma unroll
        for (int ic = 0; ic < NC_; ++ic) {
            ag += wg[c * NC_ + ic] * w[ic];
            ab += wb[c * NC_ + ic] * w[ic];
        }
        gsum += tanh_fast(silu_fast(sg[c] * ag + bg[c]));
        bmx = fmaxf(bmx, tanh_fast(silu_fast(sb[c] * ab + bb[c])));
    }
    gmap[idx] = gsum * (1.f / (float)NC_);
    bmap[idx] = bmx;
}

// ---------------- MFMA helpers ----------------
static __device__ __forceinline__ void frag_load(const short* sA, const short* sW,
                                                 int l15, int qa, int w,
                                                 bf16x8 a[8], bf16x8 bb[4])
{
#pragma unroll
    for (int m = 0; m < 8; ++m)
        a[m] = *(const bf16x8*)&sA[(m * 16 + l15) * 32 + qa * 8];
#pragma unroll
    for (int n = 0; n < 4; ++n)
        bb[n] = *(const bf16x8*)&sW[(w * 64 + n * 16 + l15) * 32 + qa * 8];
}
static __device__ __forceinline__ void frag_compute(const bf16x8 a[8], const bf16x8 bb[4],
                                                    f32x4 acc[8][4])
{
#pragma unroll
    for (int m = 0; m < 8; ++m)
#pragma unroll
        for (int n = 0; n < 4; ++n)
            acc[m][n] = __builtin_amdgcn_mfma_f32_16x16x32_bf16(a[m], bb[n], acc[m][n], 0, 0, 0);
}

// ---------------- visu conv + FiLM + l2norm -> v_film (bf16 CL) ----------------
__global__ __launch_bounds__(256, 2) void k_visu(
    const u16* __restrict__ X, const u16* __restrict__ W,
    const float* __restrict__ s_visu, const float* __restrict__ b_visu,
    const float* __restrict__ gmap, const float* __restrict__ bmap,
    u16* __restrict__ Y)
{
    int b = blockIdx.y, p0 = blockIdx.x * 128, t = threadIdx.x;
    int lane = t & 63, w = t >> 6;
    int l15 = t & 15, q = (t >> 4) & 3;
    int qa = q ^ ((l15 >> 1) & 3);
    int lc = (lane & 3) ^ ((lane >> 3) & 3);
    int lp = lane >> 2;
    __shared__ __align__(16) short SM[3 * 12288];   // 73728 B; epilogue LO = 67584 B
    __shared__ float red[4][128];
    __shared__ float invs[128];
    const u16* Xb = X + (size_t)b * CP_;

    f32x4 acc[8][4];
#pragma unroll
    for (int m = 0; m < 8; ++m)
#pragma unroll
        for (int n = 0; n < 4; ++n) acc[m][n] = (f32x4)0.f;

    auto stage = [&](int s, int buf) {
        int k0 = s * 32;
        short* bA = SM + buf * 12288;
        short* bW = bA + 4096;
#pragma unroll
        for (int i = 0; i < 2; ++i) {
            int pr = (w * 2 + i) * 16 + lp;
            gl_lds(Xb + (size_t)(p0 + pr) * C_ + k0 + lc * 8, bA + (w * 2 + i) * 512);
        }
#pragma unroll
        for (int j = 0; j < 4; ++j) {
            int oc = (w * 4 + j) * 16 + lp;
            gl_lds(W + (size_t)oc * 256 + k0 + lc * 8, bW + (w * 4 + j) * 512);
        }
    };

    stage(0, 0);
    stage(1, 1);
    VMCNT6();
    RBAR();
    int cur = 0;
    for (int s = 0; s < 8; ++s) {
        const short* bA = SM + cur * 12288;
        bf16x8 a[8], bb[4];
        frag_load(bA, bA + 4096, l15, qa, w, a, bb);
        if (s < 6) stage(s + 2, (cur == 0) ? 2 : cur - 1);
        frag_compute(a, bb, acc);
        if (s < 6) { VMCNT6(); } else { VMCNT0(); }
        RBAR();
        cur = (cur == 2) ? 0 : cur + 1;
    }

    float sc[4], sh[4];
#pragma unroll
    for (int n = 0; n < 4; ++n) {
        int oc = w * 64 + n * 16 + l15;
        sc[n] = s_visu[oc]; sh[n] = b_visu[oc];
    }
    short* LO = SM;
#pragma unroll
    for (int m = 0; m < 8; ++m) {
        f32x4 gv = *(const f32x4*)&gmap[(size_t)b * P_ + p0 + m * 16 + q * 4];
        f32x4 bm = *(const f32x4*)&bmap[(size_t)b * P_ + p0 + m * 16 + q * 4];
        float ps[4] = {0.f, 0.f, 0.f, 0.f};
#pragma unroll
        for (int n = 0; n < 4; ++n)
#pragma unroll
            for (int r = 0; r < 4; ++r) {
                float y = sc[n] * acc[m][n][r] + sh[n];
                float v = gv[r] * tanh_fast(silu_fast(y)) + bm[r];
                ps[r] += v * v;
                LO[(m * 16 + q * 4 + r) * LOS + w * 64 + n * 16 + l15] = (short)f2b(v);
            }
#pragma unroll
        for (int r = 0; r < 4; ++r) {
            float p = ps[r];
            p += __shfl_xor(p, 1);
            p += __shfl_xor(p, 2);
            p += __shfl_xor(p, 4);
            p += __shfl_xor(p, 8);
            if (l15 == 0) red[w][m * 16 + q * 4 + r] = p;
        }
    }
    __syncthreads();
    if (t < 128) {
        float s = red[0][t] + red[1][t] + red[2][t] + red[3][t];
        invs[t] = 1.f / fmaxf(sqrtf(s), 1e-12f);
    }
    __syncthreads();

    u16* Yb = Y + (size_t)b * CP_ + (size_t)p0 * C_;
#pragma unroll
    for (int h = 0; h < 2; ++h) {
        int row = h * 64 + (t >> 2);
        float inv = invs[row];
        const short* sp = &LO[row * LOS];
        u16* dp = Yb + (size_t)row * C_;
#pragma unroll
        for (int u = 0; u < 8; ++u) {
            int c = (t & 3) * 8 + u * 32;
            uint4 vv = *(const uint4*)(sp + c);
            const u16* e = (const u16*)&vv;
            uint4 o;
            u16* oe = (u16*)&o;
#pragma unroll
            for (int k = 0; k < 8; ++k) oe[k] = f2b(b2f(e[k]) * inv);
            *(uint4*)(dp + c) = o;
        }
    }
}

// ---------------- 1x1 conv (f1) + silu -> bf16 CL ----------------
__global__ __launch_bounds__(256, 2) void k_f1(
    const u16* __restrict__ X, const u16* __restrict__ W,
    const float* __restrict__ scale, const float* __restrict__ shift,
    u16* __restrict__ Y)
{
    int b = blockIdx.y, p0 = blockIdx.x * 128, t = threadIdx.x;
    int lane = t & 63, w = t >> 6;
    int l15 = t & 15, q = (t >> 4) & 3;
    int qa = q ^ ((l15 >> 1) & 3);
    int lc = (lane & 3) ^ ((lane >> 3) & 3);
    int lp = lane >> 2;
    __shared__ __align__(16) short SM[3 * 12288];
    const u16* Xb = X + (size_t)b * CP_;

    f32x4 acc[8][4];
#pragma unroll
    for (int m = 0; m < 8; ++m)
#pragma unroll
        for (int n = 0; n < 4; ++n) acc[m][n] = (f32x4)0.f;

    auto stage = [&](int s, int buf) {
        int k0 = s * 32;
        short* bA = SM + buf * 12288;
        short* bW = bA + 4096;
#pragma unroll
        for (int i = 0; i < 2; ++i) {
            int pr = (w * 2 + i) * 16 + lp;
            gl_lds(Xb + (size_t)(p0 + pr) * C_ + k0 + lc * 8, bA + (w * 2 + i) * 512);
        }
#pragma unroll
        for (int j = 0; j < 4; ++j) {
            int oc = (w * 4 + j) * 16 + lp;
            gl_lds(W + (size_t)oc * 256 + k0 + lc * 8, bW + (w * 4 + j) * 512);
        }
    };

    stage(0, 0);
    stage(1, 1);
    VMCNT6();
    RBAR();
    int cur = 0;
    for (int s = 0; s < 8; ++s) {
        const short* bA = SM + cur * 12288;
        bf16x8 a[8], bb[4];
        frag_load(bA, bA + 4096, l15, qa, w, a, bb);
        if (s < 6) stage(s + 2, (cur == 0) ? 2 : cur - 1);
        frag_compute(a, bb, acc);
        if (s < 6) { VMCNT6(); } else { VMCNT0(); }
        RBAR();
        cur = (cur == 2) ? 0 : cur + 1;
    }

    float sc[4], sh[4];
#pragma unroll
    for (int n = 0; n < 4; ++n) {
        int oc = w * 64 + n * 16 + l15;
        sc[n] = scale[oc]; sh[n] = shift[oc];
    }
    short* LO = SM;
#pragma unroll
    for (int m = 0; m < 8; ++m)
#pragma unroll
        for (int n = 0; n < 4; ++n)
#pragma unroll
            for (int r = 0; r < 4; ++r) {
                float v = silu_fast(sc[n] * acc[m][n][r] + sh[n]);
                LO[(m * 16 + q * 4 + r) * LOS + w * 64 + n * 16 + l15] = (short)f2b(v);
            }
    __syncthreads();

    u16* Yb = Y + (size_t)b * CP_ + (size_t)p0 * C_;
#pragma unroll
    for (int h = 0; h < 2; ++h) {
        int row = h * 64 + (t >> 2);
        const short* sp = &LO[row * LOS];
        u16* dp = Yb + (size_t)row * C_;
#pragma unroll
        for (int u = 0; u < 8; ++u) {
            int c = (t & 3) * 8 + u * 32;
            *(uint4*)(dp + c) = *(const uint4*)(sp + c);
        }
    }
}

// ---------------- 3x3 conv (f2): 512 threads, BM=256 x BN=256, 3-buf counted ----------------
__global__ __launch_bounds__(512, 1) void k_f2(
    const u16* __restrict__ X, const u16* __restrict__ W,
    const float* __restrict__ scale, const float* __restrict__ shift,
    const u16* __restrict__ zbig, u16* __restrict__ Y)
{
    int b = blockIdx.y, p0 = blockIdx.x * 256, t = threadIdx.x;
    int lane = t & 63, w = t >> 6;          // 8 waves
    int wr = w >> 2, wc = w & 3;            // 2 x 4 wave grid
    int l15 = t & 15, q = (t >> 4) & 3;
    int qa = q ^ ((l15 >> 1) & 3);
    int lc = (lane & 3) ^ ((lane >> 3) & 3);
    int lp = lane >> 2;
    __shared__ __align__(16) short SM[3 * 16384];   // 3 x 32KB = 96KB
    const u16* Xb = X + (size_t)b * CP_;

    f32x4 acc[8][4];
#pragma unroll
    for (int m = 0; m < 8; ++m)
#pragma unroll
        for (int n = 0; n < 4; ++n) acc[m][n] = (f32x4)0.f;

    // incremental staging: A 256px x 32k (8KB rows: wave w stages rows (w*2+i)*16+lp)
    const u16* ap0 = zbig;
    const u16* ap1 = zbig;
    const u16* wp0 = W + (size_t)((w * 2 + 0) * 16 + lp) * 2304 + lc * 8;
    const u16* wp1 = W + (size_t)((w * 2 + 1) * 16 + lp) * 2304 + lc * 8;
    int ss = 0;

    auto stage_next = [&](int buf) {
        if ((ss & 7) == 0) {
            int tap = ss >> 3;
            int dy = tap / 3 - 1, dx = tap - (tap / 3) * 3 - 1;
            int pA = p0 + (w * 2 + 0) * 16 + lp;
            int y0 = (pA >> 6) + dy, x0 = (pA & 63) + dx;
            ap0 = ((unsigned)y0 < (unsigned)HH && (unsigned)x0 < (unsigned)HH)
                  ? Xb + (size_t)(y0 * HH + x0) * C_ + lc * 8 : zbig + lc * 8;
            int pB = p0 + (w * 2 + 1) * 16 + lp;
            int y1 = (pB >> 6) + dy, x1 = (pB & 63) + dx;
            ap1 = ((unsigned)y1 < (unsigned)HH && (unsigned)x1 < (unsigned)HH)
                  ? Xb + (size_t)(y1 * HH + x1) * C_ + lc * 8 : zbig + lc * 8;
        }
        short* bA = SM + buf * 16384;
        short* bW = bA + 8192;
        gl_lds(ap0, bA + (w * 2 + 0) * 512);
        gl_lds(ap1, bA + (w * 2 + 1) * 512);
        gl_lds(wp0, bW + (w * 2 + 0) * 512);
        gl_lds(wp1, bW + (w * 2 + 1) * 512);
        ap0 += 32; ap1 += 32;
        wp0 += 32; wp1 += 32;
        ++ss;
    };

    stage_next(0);
    stage_next(1);
    VMCNT4();
    RBAR();
    int cur = 0;
    for (int s = 0; s < 72; ++s) {
        const short* bA = SM + cur * 16384;
        const short* bW = bA + 8192;
        bf16x8 a[8], bb[4];
#pragma unroll
        for (int m = 0; m < 8; ++m)
            a[m] = *(const bf16x8*)&bA[(wr * 128 + m * 16 + l15) * 32 + qa * 8];
#pragma unroll
        for (int n = 0; n < 4; ++n)
            bb[n] = *(const bf16x8*)&bW[(wc * 64 + n * 16 + l15) * 32 + qa * 8];
        if (s < 70) {
            int nb = cur == 0 ? 2 : cur - 1;   // (cur+2)%3
            stage_next(nb);
        }
        frag_compute(a, bb, acc);
        if (s < 70) { VMCNT4(); } else { VMCNT0(); }
        RBAR();
        cur = cur == 2 ? 0 : cur + 1;
    }

    float sc[4], sh[4];
#pragma unroll
    for (int n = 0; n < 4; ++n) {
        int oc = wc * 64 + n * 16 + l15;
        sc[n] = scale[oc]; sh[n] = shift[oc];
    }
    // epilogue in 2 half-tiles of 128 px (LO = 128 x LOS = 67584 shorts <= 96KB region)
    short* LO = SM;
    u16* Yb = Y + (size_t)b * CP_ + (size_t)p0 * C_;
#pragma unroll
    for (int h = 0; h < 2; ++h) {
        __syncthreads();
        if (wr == h) {
#pragma unroll
            for (int m = 0; m < 8; ++m)
#pragma unroll
                for (int n = 0; n < 4; ++n)
#pragma unroll
                    for (int r = 0; r < 4; ++r) {
                        float v = silu_fast(sc[n] * acc[m][n][r] + sh[n]);
                        LO[(m * 16 + q * 4 + r) * LOS + wc * 64 + n * 16 + l15] = (short)f2b(v);
                    }
        }
        __syncthreads();
        {
            int row = t >> 2;   // 0..127
            const short* sp = &LO[row * LOS];
            u16* dp = Yb + (size_t)(h * 128 + row) * C_;
#pragma unroll
            for (int u = 0; u < 4; ++u) {
                int c = (t & 3) * 8 + u * 64;
                *(uint4*)(dp + c) = *(const uint4*)(sp + c);
                *(uint4*)(dp + c + 32) = *(const uint4*)(sp + c + 32);
            }
        }
    }
}

// ---------------- f3 conv + bias + v_add + l2norm -> out (fp32 CF, coalesced stores) ----------------
__global__ __launch_bounds__(256, 2) void k_final(
    const u16* __restrict__ X, const u16* __restrict__ W,
    const float* __restrict__ bias_f3, const float* __restrict__ img,
    const float* __restrict__ add_w, float* __restrict__ out)
{
    int b = blockIdx.y, p0 = blockIdx.x * 128, t = threadIdx.x;
    int lane = t & 63, w = t >> 6;
    int l15 = t & 15, q = (t >> 4) & 3;
    int qa = q ^ ((l15 >> 1) & 3);
    int lc = (lane & 3) ^ ((lane >> 3) & 3);
    int lp = lane >> 2;
    __shared__ __align__(16) short SM[3 * 12288];   // 73728 B; TP uses 256*68*4 = 69632 B
    __shared__ float red[4][128];
    __shared__ float invs[128];
    const u16* Xb = X + (size_t)b * CP_;

    f32x4 acc[8][4];
#pragma unroll
    for (int m = 0; m < 8; ++m)
#pragma unroll
        for (int n = 0; n < 4; ++n) acc[m][n] = (f32x4)0.f;

    auto stage = [&](int s, int buf) {
        int k0 = s * 32;
        short* bA = SM + buf * 12288;
        short* bW = bA + 4096;
#pragma unroll
        for (int i = 0; i < 2; ++i) {
            int pr = (w * 2 + i) * 16 + lp;
            gl_lds(Xb + (size_t)(p0 + pr) * C_ + k0 + lc * 8, bA + (w * 2 + i) * 512);
        }
#pragma unroll
        for (int j = 0; j < 4; ++j) {
            int oc = (w * 4 + j) * 16 + lp;
            gl_lds(W + (size_t)oc * 256 + k0 + lc * 8, bW + (w * 4 + j) * 512);
        }
    };

    stage(0, 0);
    stage(1, 1);
    VMCNT6();
    RBAR();
    int cur = 0;
    for (int s = 0; s < 8; ++s) {
        const short* bA = SM + cur * 12288;
        bf16x8 a[8], bb[4];
        frag_load(bA, bA + 4096, l15, qa, w, a, bb);
        if (s < 6) stage(s + 2, (cur == 0) ? 2 : cur - 1);
        frag_compute(a, bb, acc);
        if (s < 6) { VMCNT6(); } else { VMCNT0(); }
        RBAR();
        cur = (cur == 2) ? 0 : cur + 1;
    }

    float aw = tanhf(add_w[0]);
    float c1 = 1.f + aw, c2 = 1.f - aw;
    float bf[4];
#pragma unroll
    for (int n = 0; n < 4; ++n) bf[n] = bias_f3[w * 64 + n * 16 + l15];

#pragma unroll
    for (int m = 0; m < 8; ++m) {
        float ps[4] = {0.f, 0.f, 0.f, 0.f};
#pragma unroll
        for (int n = 0; n < 4; ++n) {
            int oc = w * 64 + n * 16 + l15;
            f32x4 iv = *(const f32x4*)&img[((size_t)b * C_ + oc) * P_ + p0 + m * 16 + q * 4];
#pragma unroll
            for (int r = 0; r < 4; ++r) {
                float v = c1 * iv[r] + c2 * (acc[m][n][r] + bf[n]);
                acc[m][n][r] = v;
                ps[r] += v * v;
            }
        }
#pragma unroll
        for (int r = 0; r < 4; ++r) {
            float p = ps[r];
            p += __shfl_xor(p, 1);
            p += __shfl_xor(p, 2);
            p += __shfl_xor(p, 4);
            p += __shfl_xor(p, 8);
            if (l15 == 0) red[w][m * 16 + q * 4 + r] = p;
        }
    }
    __syncthreads();
    if (t < 128) {
        float s = red[0][t] + red[1][t] + red[2][t] + red[3][t];
        invs[t] = 1.f / fmaxf(sqrtf(s), 1e-12f);
    }
    __syncthreads();

    // coalesced store via LDS transpose: 2 chunks of 64 pixels; all waves active
    float* TP = (float*)SM;   // [256 oc][68] f32
#pragma unroll
    for (int cc = 0; cc < 2; ++cc) {
#pragma unroll
        for (int mm = 0; mm < 4; ++mm) {
            int m = cc * 4 + mm;
            f32x4 iv = *(const f32x4*)&invs[m * 16 + q * 4];
#pragma unroll
            for (int n = 0; n < 4; ++n) {
                int oc = w * 64 + n * 16 + l15;
                f32x4 o;
#pragma unroll
                for (int r = 0; r < 4; ++r) o[r] = acc[m][n][r] * iv[r];
                *(f32x4*)&TP[(size_t)oc * 68 + mm * 16 + q * 4] = o;
            }
        }
        __syncthreads();
        {
            int c16 = (t & 15) * 4;
#pragma unroll
            for (int u = 0; u < 16; ++u) {
                int row = u * 16 + (t >> 4);
                *(f32x4*)&out[((size_t)b * C_ + row) * P_ + p0 + cc * 64 + c16] =
                    *(const f32x4*)&TP[(size_t)row * 68 + c16];
            }
        }
        __syncthreads();
    }
}

extern "C" void kernel_launch(void* const* d_in, const int* in_sizes, int n_in,
                              void* d_out, int out_size, void* d_ws, size_t ws_size,
                              hipStream_t stream)
{
    const float* img     = (const float*)d_in[0];
    const float* flang   = (const float*)d_in[1];
    const int*   wmask   = (const int*)d_in[2];
    const float* w_visu  = (const float*)d_in[3];
    const float* s_visu  = (const float*)d_in[4];
    const float* b_visu  = (const float*)d_in[5];
    const float* w_g     = (const float*)d_in[6];
    const float* s_g     = (const float*)d_in[7];
    const float* b_g     = (const float*)d_in[8];
    const float* w_b     = (const float*)d_in[9];
    const float* s_b     = (const float*)d_in[10];
    const float* b_b     = (const float*)d_in[11];
    const float* W1      = (const float*)d_in[12];
    const float* b1      = (const float*)d_in[13];
    const float* W2      = (const float*)d_in[14];
    const float* b2      = (const float*)d_in[15];
    const float* w_f1    = (const float*)d_in[16];
    const float* s_f1    = (const float*)d_in[17];
    const float* b_f1    = (const float*)d_in[18];
    const float* w_f2    = (const float*)d_in[19];
    const float* s_f2    = (const float*)d_in[20];
    const float* b_f2    = (const float*)d_in[21];
    const float* w_f3    = (const float*)d_in[22];
    const float* bias_f3 = (const float*)d_in[23];
    const float* add_w   = (const float*)d_in[24];

    float* out = (float*)d_out;

    // workspace layout (u16 elements)
    u16* bigA = (u16*)d_ws;                 // 33554432: v_film, then v2
    u16* bigB = bigA + (size_t)B_ * CP_;    // 33554432: imgT, then v
    u16* WV   = bigB + (size_t)B_ * CP_;    // 65536
    u16* WF1  = WV + 65536;                 // 65536
    u16* WF3  = WF1 + 65536;                // 65536
    u16* WF2  = WF3 + 65536;                // 589824
    float* gmap = (float*)(WF2 + 589824);   // 131072 f32
    float* bmap = gmap + (size_t)B_ * P_;   // 131072 f32
    int* centers = (int*)(bmap + (size_t)B_ * P_);  // 512 ints
    u16* zbig = (u16*)(centers + 512);      // 1024 u16 zero block

    k_prep<<<256, 256, 0, stream>>>(w_visu, w_f1, w_f3, w_f2, WV, WF1, WF3, WF2, zbig);
    k_lang<<<B_, 256, 0, stream>>>(flang, wmask, W1, b1, W2, b2, centers);
    k_gb<<<(B_ * P_) / 256, 256, 0, stream>>>(centers, w_g, s_g, b_g, w_b, s_b, b_b, gmap, bmap);
    k_imgT<<<dim3(P_ / 32, C_ / 32, B_), 256, 0, stream>>>(img, bigB);
    k_visu<<<dim3(P_ / 128, B_), 256, 0, stream>>>(bigB, WV, s_visu, b_visu, gmap, bmap, bigA);
    k_f1<<<dim3(P_ / 128, B_), 256, 0, stream>>>(bigA, WF1, s_f1, b_f1, bigB);
    k_f2<<<dim3(P_ / 256, B_), 512, 0, stream>>>(bigB, WF2, s_f2, b_f2, zbig, bigA);
    k_final<<<dim3(P_ / 128, B_), 256, 0, stream>>>(bigA, WF3, bias_f3, img, add_w, out);
}